// Round 3
// baseline (166.701 us; speedup 1.0000x reference)
//
#include <hip/hip_runtime.h>
#include <hip/hip_cooperative_groups.h>
#include <math.h>

namespace cg = cooperative_groups;

#define D_DIM 128
#define K_DIM 64
#define R_DIM 8
#define B_DIM 8192
#define XSTR  264            // ushort per staged X row (256 data + 8 pad)
#define NTILE (B_DIM / 16)   // 512 row-tiles

// ws layout (compact T):
//   T  : bf16, per kg (4 of them) 40 tiles of [16 kl][32 pos] ushort:
//        tiles 0..35  = y-part   : tile = chunk*9 + cc  (chunk 0..3, cc 0..8)
//                       cc 0..7 = W/sqrt2, cc 8 = h'
//        tiles 36..39 = y^2-part : tile = 36 + chunk    (-0.5*s_inv)
//        per-kg size 40*512 = 20480 ushort; total 81920 ushort = 40960 floats
//   c0 : float [K] at 40960
#define WS_C0F   40960

typedef __bf16 bf16x8 __attribute__((ext_vector_type(8)));
typedef float  f32x4  __attribute__((ext_vector_type(4)));

static __device__ inline unsigned short f2bf(float f) {
  union { float f; unsigned int u; } v; v.f = f;
  unsigned int u = v.u;
  unsigned int lsb = (u >> 16) & 1;
  u += 0x7fffu + lsb;                 // round-to-nearest-even
  return (unsigned short)(u >> 16);
}

// Stage X = [bf16(y), bf16(y^2)] for row-tile `tile` into sX. 256 threads.
static __device__ inline void stage_x(unsigned short* sX, const float* y,
                                      int tile, int tid) {
#pragma unroll
  for (int j = 0; j < 2; ++j) {
    const int idx = tid + j * 256;        // granule 0..511
    const int row = idx >> 5, g = idx & 31;
    const float4* ya = (const float4*)y + (size_t)(tile * 16 + row) * 32 + (g & 15) * 2;
    float4 a = ya[0], b = ya[1];
    if (g >= 16) {
      a.x *= a.x; a.y *= a.y; a.z *= a.z; a.w *= a.w;
      b.x *= b.x; b.y *= b.y; b.z *= b.z; b.w *= b.w;
    }
    union { unsigned short us[8]; uint4 v; } o;
    o.us[0] = f2bf(a.x); o.us[1] = f2bf(a.y); o.us[2] = f2bf(a.z); o.us[3] = f2bf(a.w);
    o.us[4] = f2bf(b.x); o.us[5] = f2bf(b.y); o.us[6] = f2bf(b.z); o.us[7] = f2bf(b.w);
    *(uint4*)(sX + row * XSTR + g * 8) = o.v;
  }
}

// ---------------------------------------------------------------------------
// Fused cooperative kernel. Blocks 0..63 = producers: per-k precompute
// (k = bid) into ws. ALL blocks then stage their first X tile (overlapping
// the producers' work), hit grid.sync() (cooperative launch guarantees
// co-residency -> no deadlock by construction), and run the barrier-free
// MFMA main loop + logsumexp epilogue, grid-striding over the 512 tiles.
// ---------------------------------------------------------------------------
__global__ __launch_bounds__(256, 2) void logz_fused(
    const float* __restrict__ y, const float* __restrict__ m,
    const float* __restrict__ delta, const float* __restrict__ U,
    const float* __restrict__ lar, float* __restrict__ ws,
    float* __restrict__ out) {
  __shared__ __align__(16) unsigned short sX[16 * XSTR];  // 8448 B
  __shared__ float vals2[16 * 66];                        // 4224 B
  // producer scratch (~17 KB; blocks 0..63 only)
  __shared__ float U_l[D_DIM][R_DIM];
  __shared__ float V_l[D_DIM][R_DIM];
  __shared__ float W_l[D_DIM][R_DIM];
  __shared__ float m_l[D_DIM];
  __shared__ float red[64];
  __shared__ float Linv_s[R_DIM][R_DIM];
  __shared__ float q_s[R_DIM];
  __shared__ float c0_s[1];
  __shared__ float part[4][3];

  cg::grid_group grid = cg::this_grid();

  const int tid   = threadIdx.x;            // 0..255
  const int bid   = (int)blockIdx.x;
  const int nblk  = (int)gridDim.x;
  const int lane  = tid & 63;
  const int wv    = tid >> 6;               // 0..3 = col-wave = kg
  const int col_l = lane & 15;
  const int quad  = lane >> 4;

  if (bid < K_DIM) {
    // ================= producer: per-k precompute, k = bid ================
    const int k = bid, d = tid;
    float dl = 0.f, s_inv = 0.f, mv = 0.f;
    float Wr[R_DIM];
    if (d < D_DIM) {
      dl    = delta[k * D_DIM + d];
      s_inv = expf(-dl);
      mv    = m[k * D_DIM + d];
      m_l[d] = mv;
      const float* Up = U + (size_t)(k * D_DIM + d) * R_DIM;
#pragma unroll
      for (int r = 0; r < R_DIM; ++r) {
        float u = Up[r];
        U_l[d][r] = u;
        V_l[d][r] = u * s_inv;
      }
    }
    // 3-way reductions via wave shuffles (waves 2,3 contribute zeros)
    {
      float pA = dl;
      float pB = mv * mv * s_inv;
      float pC = (d < K_DIM) ? lar[d] : 0.f;
#pragma unroll
      for (int off = 32; off > 0; off >>= 1) {
        pA += __shfl_xor(pA, off, 64);
        pB += __shfl_xor(pB, off, 64);
        pC += __shfl_xor(pC, off, 64);
      }
      if (lane == 0) { part[wv][0] = pA; part[wv][1] = pB; part[wv][2] = pC; }
    }
    __syncthreads();                 // U_l/V_l/m_l + partials visible

    if (d < 64) {                    // Gram: M = I + U^T diag(s_inv) U
      const int r = d >> 3, s = d & 7;
      float acc = (r == s) ? 1.0f : 0.0f;
#pragma unroll 8
      for (int dd = 0; dd < D_DIM; ++dd) acc += U_l[dd][r] * V_l[dd][s];
      red[d] = acc;
    }
    __syncthreads();

    if (d == 0) {
      float Lm[8][8];
#pragma unroll
      for (int i = 0; i < 8; ++i) {
#pragma unroll
        for (int j = 0; j < 8; ++j) {
          if (j > i) continue;
          float sum = red[i * 8 + j];
#pragma unroll
          for (int p = 0; p < 8; ++p)
            if (p < j) sum -= Lm[i][p] * Lm[j][p];
          if (i == j) Lm[i][i] = sqrtf(sum);
          else        Lm[i][j] = sum / Lm[j][j];
        }
      }
      float ld = 0.f;
#pragma unroll
      for (int i = 0; i < 8; ++i) ld += logf(Lm[i][i]);

      float Li[8][8];
#pragma unroll
      for (int i = 0; i < 8; ++i)
#pragma unroll
        for (int j = 0; j < 8; ++j) Li[i][j] = 0.f;
#pragma unroll
      for (int j = 0; j < 8; ++j) {
        Li[j][j] = 1.0f / Lm[j][j];
#pragma unroll
        for (int i = 0; i < 8; ++i) {
          if (i <= j) continue;
          float sum = 0.f;
#pragma unroll
          for (int p = 0; p < 8; ++p)
            if (p >= j && p < i) sum += Lm[i][p] * Li[p][j];
          Li[i][j] = -sum / Lm[i][i];
        }
      }
#pragma unroll
      for (int i = 0; i < 8; ++i)
#pragma unroll
        for (int j = 0; j < 8; ++j) Linv_s[i][j] = Li[i][j];

      const float sA = part[0][0] + part[1][0] + part[2][0] + part[3][0];
      const float sB = part[0][1] + part[1][1] + part[2][1] + part[3][1];
      const float sC = part[0][2] + part[1][2] + part[2][2] + part[3][2];
      const float mean = sC * (1.0f / K_DIM);
      const float log_alpha = lar[k] - mean;       // /eps, eps=1
      const float logdetS = sA + 2.0f * ld;
      const float LOG2PI = 1.8378770664093453f;
      const float log_norm = 0.5f * ((float)D_DIM * LOG2PI + logdetS);
      c0_s[0] = log_alpha - log_norm - 0.5f * sB;
    }
    __syncthreads();

    if (d < D_DIM) {                 // W = diag(s_inv) U L^-T  (lower Linv)
#pragma unroll
      for (int r = 0; r < R_DIM; ++r) {
        float acc = 0.f;
#pragma unroll
        for (int s2 = 0; s2 < R_DIM; ++s2)
          if (s2 <= r) acc += V_l[d][s2] * Linv_s[r][s2];
        Wr[r] = acc;
        W_l[d][r] = acc;
      }
    }
    __syncthreads();

    if (d < R_DIM) {                 // q = W^T m
      float acc = 0.f;
#pragma unroll 8
      for (int dd = 0; dd < D_DIM; ++dd) acc += W_l[dd][d] * m_l[dd];
      q_s[d] = acc;
    }
    __syncthreads();

    if (d < D_DIM) {
      float hp = mv * s_inv;
#pragma unroll
      for (int r = 0; r < R_DIM; ++r) hp -= q_s[r] * Wr[r];

      const float INV_SQRT2 = 0.70710678118654752f;
      unsigned short* T = (unsigned short*)ws;
      const int kg = k >> 4, kl = k & 15;
      const int chunk = d >> 5, pos = d & 31;
      const size_t kgbase = (size_t)kg * 20480;
      const size_t by = kgbase + ((size_t)(chunk * 9) * 16 + kl) * 32 + pos;
#pragma unroll
      for (int cc = 0; cc < 8; ++cc)
        T[by + (size_t)cc * 512] = f2bf(Wr[cc] * INV_SQRT2);
      T[by + 8 * 512] = f2bf(hp);
      const size_t bq = kgbase + ((size_t)(36 + chunk) * 16 + kl) * 32 + pos;
      T[bq] = f2bf(-0.5f * s_inv);
    }
    if (d == 0) {
      float qq = 0.f;
#pragma unroll
      for (int r = 0; r < R_DIM; ++r) qq += q_s[r] * q_s[r];
      ws[WS_C0F + k] = c0_s[0] + 0.5f * qq;   // c0' = c0 + 0.5*||q||^2
    }
  }

  // stage first X tile (all blocks; overlaps producers' precompute)
  stage_x(sX, y, bid, tid);

  __threadfence();                 // release producer T writes (L2 writeback)
  grid.sync();                     // co-residency guaranteed by coop launch
  __threadfence();                 // acquire: invalidate stale L2 before T reads

  // ---- barrier-free MFMA main loop, grid-stride over tiles ----
  const float cv = ws[WS_C0F + wv * 16 + col_l];
  const unsigned short* Tb = (const unsigned short*)ws
      + (size_t)wv * 20480 + col_l * 32 + quad * 8;

  bool first = true;
  for (int t = bid; t < NTILE; t += nblk) {
    if (!first) {
      __syncthreads();             // prior tile's sX/vals2 reads complete
      stage_x(sX, y, t, tid);
      __syncthreads();
    }
    first = false;

    bf16x8 a[8];
#pragma unroll
    for (int c = 0; c < 8; ++c)
      a[c] = *(const bf16x8*)(sX + col_l * XSTR + c * 32 + quad * 8);

    f32x4 acc[9];
#pragma unroll
    for (int f = 0; f < 9; ++f) { acc[f][0] = 0.f; acc[f][1] = 0.f; acc[f][2] = 0.f; acc[f][3] = 0.f; }

    bf16x8 bq[4];
#pragma unroll
    for (int c = 0; c < 4; ++c)
      bq[c] = *(const bf16x8*)(Tb + (size_t)(36 + c) * 512);

#pragma unroll
    for (int c = 0; c < 4; ++c) {
      bf16x8 b[9];
#pragma unroll
      for (int f = 0; f < 9; ++f)
        b[f] = *(const bf16x8*)(Tb + (size_t)(c * 9 + f) * 512);
#pragma unroll
      for (int f = 0; f < 9; ++f)
        acc[f] = __builtin_amdgcn_mfma_f32_16x16x32_bf16(a[c], b[f], acc[f], 0, 0, 0);
    }
#pragma unroll
    for (int c = 0; c < 4; ++c)
      acc[8] = __builtin_amdgcn_mfma_f32_16x16x32_bf16(a[4 + c], bq[c], acc[8], 0, 0, 0);

    // ---- epilogue: per-k logits in registers ----
#pragma unroll
    for (int reg = 0; reg < 4; ++reg) {
      float v = acc[8][reg];                  // linear + diag term
#pragma unroll
      for (int cc = 0; cc < 8; ++cc) v += acc[cc][reg] * acc[cc][reg];
      vals2[(quad * 4 + reg) * 66 + wv * 16 + col_l] = cv + v;
    }
    __syncthreads();

    // per-row 64-k logsumexp: wave wv handles rows wv*4..wv*4+3, lane = k
#pragma unroll
    for (int rr = 0; rr < 4; ++rr) {
      const int row = wv * 4 + rr;
      const float val = vals2[row * 66 + lane];
      float mx = val;
#pragma unroll
      for (int off = 1; off < 64; off <<= 1)
        mx = fmaxf(mx, __shfl_xor(mx, off, 64));
      float ex = expf(val - mx);
#pragma unroll
      for (int off = 1; off < 64; off <<= 1)
        ex += __shfl_xor(ex, off, 64);
      if (lane == 0) out[t * 16 + row] = mx + logf(ex);
    }
  }
}

// ---------------------------------------------------------------------------
// Fallback path (round-1 proven kernels, 78.2 us): used if cooperative
// launch is rejected by the runtime/capture.
// ---------------------------------------------------------------------------
__global__ __launch_bounds__(128) void precomp_kernel(
    const float* __restrict__ m, const float* __restrict__ delta,
    const float* __restrict__ U, const float* __restrict__ lar,
    float* __restrict__ ws) {
  const int k = blockIdx.x;
  const int d = threadIdx.x;  // 0..127

  __shared__ float U_l[D_DIM][R_DIM];
  __shared__ float V_l[D_DIM][R_DIM];
  __shared__ float W_l[D_DIM][R_DIM];
  __shared__ float m_l[D_DIM];
  __shared__ float red[64];
  __shared__ float Linv_s[R_DIM][R_DIM];
  __shared__ float q_s[R_DIM];
  __shared__ float c0_s[1];
  __shared__ float redA[D_DIM], redB[D_DIM], redC[D_DIM];

  const float dl    = delta[k * D_DIM + d];
  const float s_inv = expf(-dl);
  const float mv    = m[k * D_DIM + d];
  m_l[d] = mv;
  const float* Up = U + (size_t)(k * D_DIM + d) * R_DIM;
#pragma unroll
  for (int r = 0; r < R_DIM; ++r) {
    float u = Up[r];
    U_l[d][r] = u;
    V_l[d][r] = u * s_inv;
  }
  redA[d] = dl;
  redB[d] = mv * mv * s_inv;
  redC[d] = (d < K_DIM) ? lar[d] : 0.f;
  __syncthreads();

  if (d < 64) {
    const int r = d >> 3, s = d & 7;
    float acc = (r == s) ? 1.0f : 0.0f;
#pragma unroll 8
    for (int dd = 0; dd < D_DIM; ++dd) acc += U_l[dd][r] * V_l[dd][s];
    red[d] = acc;
  }
  __syncthreads();

  for (int off = 64; off > 0; off >>= 1) {
    if (d < off) {
      redA[d] += redA[d + off];
      redB[d] += redB[d + off];
      redC[d] += redC[d + off];
    }
    __syncthreads();
  }

  if (d == 0) {
    float Lm[8][8];
#pragma unroll
    for (int i = 0; i < 8; ++i) {
#pragma unroll
      for (int j = 0; j < 8; ++j) {
        if (j > i) continue;
        float sum = red[i * 8 + j];
#pragma unroll
        for (int p = 0; p < 8; ++p)
          if (p < j) sum -= Lm[i][p] * Lm[j][p];
        if (i == j) Lm[i][i] = sqrtf(sum);
        else        Lm[i][j] = sum / Lm[j][j];
      }
    }
    float ld = 0.f;
#pragma unroll
    for (int i = 0; i < 8; ++i) ld += logf(Lm[i][i]);

    float Li[8][8];
#pragma unroll
    for (int i = 0; i < 8; ++i)
#pragma unroll
      for (int j = 0; j < 8; ++j) Li[i][j] = 0.f;
#pragma unroll
    for (int j = 0; j < 8; ++j) {
      Li[j][j] = 1.0f / Lm[j][j];
#pragma unroll
      for (int i = 0; i < 8; ++i) {
        if (i <= j) continue;
        float sum = 0.f;
#pragma unroll
        for (int p = 0; p < 8; ++p)
          if (p >= j && p < i) sum += Lm[i][p] * Li[p][j];
        Li[i][j] = -sum / Lm[i][i];
      }
    }
#pragma unroll
    for (int i = 0; i < 8; ++i)
#pragma unroll
      for (int j = 0; j < 8; ++j) Linv_s[i][j] = Li[i][j];

    const float mean = redC[0] * (1.0f / K_DIM);
    const float log_alpha = lar[k] - mean;
    const float logdetS = redA[0] + 2.0f * ld;
    const float LOG2PI = 1.8378770664093453f;
    const float log_norm = 0.5f * ((float)D_DIM * LOG2PI + logdetS);
    c0_s[0] = log_alpha - log_norm - 0.5f * redB[0];
  }
  __syncthreads();

  float Wr[R_DIM];
#pragma unroll
  for (int r = 0; r < R_DIM; ++r) {
    float acc = 0.f;
#pragma unroll
    for (int s2 = 0; s2 < R_DIM; ++s2)
      if (s2 <= r) acc += V_l[d][s2] * Linv_s[r][s2];
    Wr[r] = acc;
    W_l[d][r] = acc;
  }
  __syncthreads();

  if (d < R_DIM) {
    float acc = 0.f;
#pragma unroll 8
    for (int dd = 0; dd < D_DIM; ++dd) acc += W_l[dd][d] * m_l[dd];
    q_s[d] = acc;
  }
  __syncthreads();

  float hp = mv * s_inv;
#pragma unroll
  for (int r = 0; r < R_DIM; ++r) hp -= q_s[r] * Wr[r];

  const float INV_SQRT2 = 0.70710678118654752f;
  unsigned short* T = (unsigned short*)ws;
  const int kg = k >> 4, kl = k & 15;
  const int chunk = d >> 5, pos = d & 31;
  const size_t kgbase = (size_t)kg * 20480;
  const size_t by = kgbase + ((size_t)(chunk * 9) * 16 + kl) * 32 + pos;
#pragma unroll
  for (int cc = 0; cc < 8; ++cc)
    T[by + (size_t)cc * 512] = f2bf(Wr[cc] * INV_SQRT2);
  T[by + 8 * 512] = f2bf(hp);
  const size_t bq = kgbase + ((size_t)(36 + chunk) * 16 + kl) * 32 + pos;
  T[bq] = f2bf(-0.5f * s_inv);

  if (d == 0) {
    float qq = 0.f;
#pragma unroll
    for (int r = 0; r < R_DIM; ++r) qq += q_s[r] * q_s[r];
    ws[WS_C0F + k] = c0_s[0] + 0.5f * qq;
  }
}

__global__ __launch_bounds__(256) void logz_full(
    const float* __restrict__ y, const float* __restrict__ ws,
    float* __restrict__ out) {
  __shared__ __align__(16) unsigned short sX[16 * XSTR];
  __shared__ float vals2[16 * 66];

  const int tid   = threadIdx.x;
  const int lane  = tid & 63;
  const int wv    = tid >> 6;
  const int col_l = lane & 15;
  const int quad  = lane >> 4;

  stage_x(sX, y, (int)blockIdx.x, tid);

  const float cv = ws[WS_C0F + wv * 16 + col_l];
  __syncthreads();

  const unsigned short* Tb = (const unsigned short*)ws
      + (size_t)wv * 20480 + col_l * 32 + quad * 8;

  bf16x8 a[8];
#pragma unroll
  for (int c = 0; c < 8; ++c)
    a[c] = *(const bf16x8*)(sX + col_l * XSTR + c * 32 + quad * 8);

  f32x4 acc[9];
#pragma unroll
  for (int f = 0; f < 9; ++f) { acc[f][0] = 0.f; acc[f][1] = 0.f; acc[f][2] = 0.f; acc[f][3] = 0.f; }

  bf16x8 bq[4];
#pragma unroll
  for (int c = 0; c < 4; ++c)
    bq[c] = *(const bf16x8*)(Tb + (size_t)(36 + c) * 512);

#pragma unroll
  for (int c = 0; c < 4; ++c) {
    bf16x8 b[9];
#pragma unroll
    for (int f = 0; f < 9; ++f)
      b[f] = *(const bf16x8*)(Tb + (size_t)(c * 9 + f) * 512);
#pragma unroll
    for (int f = 0; f < 9; ++f)
      acc[f] = __builtin_amdgcn_mfma_f32_16x16x32_bf16(a[c], b[f], acc[f], 0, 0, 0);
  }
#pragma unroll
  for (int c = 0; c < 4; ++c)
    acc[8] = __builtin_amdgcn_mfma_f32_16x16x32_bf16(a[4 + c], bq[c], acc[8], 0, 0, 0);

#pragma unroll
  for (int reg = 0; reg < 4; ++reg) {
    float v = acc[8][reg];
#pragma unroll
    for (int cc = 0; cc < 8; ++cc) v += acc[cc][reg] * acc[cc][reg];
    vals2[(quad * 4 + reg) * 66 + wv * 16 + col_l] = cv + v;
  }
  __syncthreads();

#pragma unroll
  for (int rr = 0; rr < 4; ++rr) {
    const int row = wv * 4 + rr;
    const float val = vals2[row * 66 + lane];
    float mx = val;
#pragma unroll
    for (int off = 1; off < 64; off <<= 1)
      mx = fmaxf(mx, __shfl_xor(mx, off, 64));
    float ex = expf(val - mx);
#pragma unroll
    for (int off = 1; off < 64; off <<= 1)
      ex += __shfl_xor(ex, off, 64);
    if (lane == 0) out[(int)blockIdx.x * 16 + row] = mx + logf(ex);
  }
}

extern "C" void kernel_launch(void* const* d_in, const int* in_sizes, int n_in,
                              void* d_out, int out_size, void* d_ws, size_t ws_size,
                              hipStream_t stream) {
  const float* y     = (const float*)d_in[0];
  const float* m     = (const float*)d_in[1];
  const float* delta = (const float*)d_in[2];
  const float* U     = (const float*)d_in[3];
  const float* lar   = (const float*)d_in[4];
  float* out = (float*)d_out;
  float* ws  = (float*)d_ws;

  static int  nblk = 0;
  static bool coop_bad = false;

  if (nblk == 0) {
    int occ = 0;
    if (hipOccupancyMaxActiveBlocksPerMultiprocessor(&occ, logz_fused, 256, 0)
            != hipSuccess || occ < 1)
      occ = 1;
    int ncu = 256;
    int dev = 0;
    hipDeviceProp_t prop;
    if (hipGetDevice(&dev) == hipSuccess &&
        hipGetDeviceProperties(&prop, dev) == hipSuccess &&
        prop.multiProcessorCount > 0)
      ncu = prop.multiProcessorCount;
    long cap = (long)occ * (long)ncu;
    nblk = (int)(cap < NTILE ? cap : NTILE);
    if (nblk < K_DIM) nblk = K_DIM;   // producers must all fit (>=256 CUs anyway)
  }

  if (!coop_bad) {
    void* args[] = {(void*)&y, (void*)&m, (void*)&delta, (void*)&U,
                    (void*)&lar, (void*)&ws, (void*)&out};
    hipError_t err = hipLaunchCooperativeKernel(
        (const void*)logz_fused, dim3(nblk), dim3(256), args, 0, stream);
    if (err == hipSuccess) return;
    coop_bad = true;
    (void)hipGetLastError();          // clear sticky error, fall through
  }

  // fallback: proven two-kernel path
  precomp_kernel<<<K_DIM, 128, 0, stream>>>(m, delta, U, lar, ws);
  logz_full<<<B_DIM / 16, 256, 0, stream>>>(y, ws, out);
}

// Round 4
// 77.725 us; speedup vs baseline: 2.1448x; 2.1448x over previous
//
#include <hip/hip_runtime.h>
#include <math.h>

#define D_DIM 128
#define K_DIM 64
#define R_DIM 8
#define B_DIM 8192
#define XSTR  264        // ushort per staged X row (256 data + 8 pad)

// ws layout (compact T):
//   T  : bf16, per kg (4 of them) 40 tiles of [16 kl][32 pos] ushort:
//        tiles 0..35  = y-part   : tile = chunk*9 + cc  (chunk 0..3, cc 0..8)
//                       cc 0..7 = W/sqrt2, cc 8 = h'
//        tiles 36..39 = y^2-part : tile = 36 + chunk    (-0.5*s_inv)
//        per-kg size 40*512 = 20480 ushort; total 81920 ushort = 40960 floats
//   c0 : float [K] at 40960
#define WS_C0F   40960

typedef __bf16 bf16x8 __attribute__((ext_vector_type(8)));
typedef float  f32x4  __attribute__((ext_vector_type(4)));

static __device__ inline unsigned short f2bf(float f) {
  union { float f; unsigned int u; } v; v.f = f;
  unsigned int u = v.u;
  unsigned int lsb = (u >> 16) & 1;
  u += 0x7fffu + lsb;                 // round-to-nearest-even
  return (unsigned short)(u >> 16);
}

// ---------------------------------------------------------------------------
// Per-k precompute. Grid = K blocks, 128 threads (2 waves). Tree reductions
// replaced by wave shuffle + 2-entry LDS combine: 5 barriers instead of 11.
// ---------------------------------------------------------------------------
__global__ __launch_bounds__(128) void precomp_kernel(
    const float* __restrict__ m, const float* __restrict__ delta,
    const float* __restrict__ U, const float* __restrict__ lar,
    float* __restrict__ ws) {
  const int k = blockIdx.x;
  const int d = threadIdx.x;  // 0..127

  __shared__ float U_l[D_DIM][R_DIM];
  __shared__ float V_l[D_DIM][R_DIM];
  __shared__ float W_l[D_DIM][R_DIM];
  __shared__ float m_l[D_DIM];
  __shared__ float red[64];
  __shared__ float Linv_s[R_DIM][R_DIM];
  __shared__ float q_s[R_DIM];
  __shared__ float c0_s[1];
  __shared__ float part[2][3];

  const int lane = d & 63;
  const int wv   = d >> 6;            // 0..1

  const float dl    = delta[k * D_DIM + d];
  const float s_inv = expf(-dl);
  const float mv    = m[k * D_DIM + d];
  m_l[d] = mv;
  const float* Up = U + (size_t)(k * D_DIM + d) * R_DIM;
#pragma unroll
  for (int r = 0; r < R_DIM; ++r) {
    float u = Up[r];
    U_l[d][r] = u;
    V_l[d][r] = u * s_inv;
  }
  // 3-way reduction via wave shuffles (wave 1 contributes 0 to C)
  {
    float pA = dl;
    float pB = mv * mv * s_inv;
    float pC = (d < K_DIM) ? lar[d] : 0.f;
#pragma unroll
    for (int off = 32; off > 0; off >>= 1) {
      pA += __shfl_xor(pA, off, 64);
      pB += __shfl_xor(pB, off, 64);
      pC += __shfl_xor(pC, off, 64);
    }
    if (lane == 0) { part[wv][0] = pA; part[wv][1] = pB; part[wv][2] = pC; }
  }
  __syncthreads();                    // U_l/V_l/m_l + partials visible

  if (d < 64) {                       // Gram: M = I + U^T diag(s_inv) U
    const int r = d >> 3, s = d & 7;
    float acc = (r == s) ? 1.0f : 0.0f;
#pragma unroll 8
    for (int dd = 0; dd < D_DIM; ++dd) acc += U_l[dd][r] * V_l[dd][s];
    red[d] = acc;
  }
  __syncthreads();

  if (d == 0) {
    float Lm[8][8];
#pragma unroll
    for (int i = 0; i < 8; ++i) {
#pragma unroll
      for (int j = 0; j < 8; ++j) {
        if (j > i) continue;
        float sum = red[i * 8 + j];
#pragma unroll
        for (int p = 0; p < 8; ++p)
          if (p < j) sum -= Lm[i][p] * Lm[j][p];
        if (i == j) Lm[i][i] = sqrtf(sum);
        else        Lm[i][j] = sum / Lm[j][j];
      }
    }
    float ld = 0.f;
#pragma unroll
    for (int i = 0; i < 8; ++i) ld += logf(Lm[i][i]);

    float Li[8][8];
#pragma unroll
    for (int i = 0; i < 8; ++i)
#pragma unroll
      for (int j = 0; j < 8; ++j) Li[i][j] = 0.f;
#pragma unroll
    for (int j = 0; j < 8; ++j) {
      Li[j][j] = 1.0f / Lm[j][j];
#pragma unroll
      for (int i = 0; i < 8; ++i) {
        if (i <= j) continue;
        float sum = 0.f;
#pragma unroll
        for (int p = 0; p < 8; ++p)
          if (p >= j && p < i) sum += Lm[i][p] * Li[p][j];
        Li[i][j] = -sum / Lm[i][i];
      }
    }
#pragma unroll
    for (int i = 0; i < 8; ++i)
#pragma unroll
      for (int j = 0; j < 8; ++j) Linv_s[i][j] = Li[i][j];

    const float sA = part[0][0] + part[1][0];
    const float sB = part[0][1] + part[1][1];
    const float sC = part[0][2] + part[1][2];
    const float mean = sC * (1.0f / K_DIM);
    const float log_alpha = lar[k] - mean;       // /eps, eps=1
    const float logdetS = sA + 2.0f * ld;
    const float LOG2PI = 1.8378770664093453f;
    const float log_norm = 0.5f * ((float)D_DIM * LOG2PI + logdetS);
    c0_s[0] = log_alpha - log_norm - 0.5f * sB;
  }
  __syncthreads();

  float Wr[R_DIM];
#pragma unroll
  for (int r = 0; r < R_DIM; ++r) {   // W = diag(s_inv) U L^-T (lower Linv)
    float acc = 0.f;
#pragma unroll
    for (int s2 = 0; s2 < R_DIM; ++s2)
      if (s2 <= r) acc += V_l[d][s2] * Linv_s[r][s2];
    Wr[r] = acc;
    W_l[d][r] = acc;
  }
  __syncthreads();

  if (d < R_DIM) {                    // q = W^T m
    float acc = 0.f;
#pragma unroll 8
    for (int dd = 0; dd < D_DIM; ++dd) acc += W_l[dd][d] * m_l[dd];
    q_s[d] = acc;
  }
  __syncthreads();

  float hp = mv * s_inv;
#pragma unroll
  for (int r = 0; r < R_DIM; ++r) hp -= q_s[r] * Wr[r];

  const float INV_SQRT2 = 0.70710678118654752f;
  unsigned short* T = (unsigned short*)ws;
  const int kg = k >> 4, kl = k & 15;
  const int chunk = d >> 5, pos = d & 31;
  const size_t kgbase = (size_t)kg * 20480;
  const size_t by = kgbase + ((size_t)(chunk * 9) * 16 + kl) * 32 + pos;
#pragma unroll
  for (int cc = 0; cc < 8; ++cc)
    T[by + (size_t)cc * 512] = f2bf(Wr[cc] * INV_SQRT2);
  T[by + 8 * 512] = f2bf(hp);
  const size_t bq = kgbase + ((size_t)(36 + chunk) * 16 + kl) * 32 + pos;
  T[bq] = f2bf(-0.5f * s_inv);

  if (d == 0) {
    float qq = 0.f;
#pragma unroll
    for (int r = 0; r < R_DIM; ++r) qq += q_s[r] * q_s[r];
    ws[WS_C0F + k] = c0_s[0] + 0.5f * qq;   // c0' = c0 + 0.5*||q||^2
  }
}

// ---------------------------------------------------------------------------
// Fused MFMA kernel, barrier-free main loop, T read straight from L2.
// Change vs round 1: cv / bq / chunk-0 T loads are issued BEFORE the X
// conversion, so their L2 latency hides under the conversion VALU work and
// MFMAs can start immediately after the single barrier.
// Grid = 512 blocks x 256 threads (4 waves, wave = one kg).
// ---------------------------------------------------------------------------
__global__ __launch_bounds__(256) void logz_full(
    const float* __restrict__ y, const float* __restrict__ ws,
    float* __restrict__ out) {
  __shared__ __align__(16) unsigned short sX[16 * XSTR];        // 8448 B
  __shared__ float vals2[16 * 66];                              // 4224 B

  const int tid   = threadIdx.x;            // 0..255
  const int lane  = tid & 63;
  const int wv    = tid >> 6;               // 0..3 = col-wave = kg
  const int col_l = lane & 15;
  const int quad  = lane >> 4;
  const int r0    = (int)blockIdx.x * 16;

  // ---- early global loads: issue before the conversion VALU work ----
  const float cv = ws[WS_C0F + wv * 16 + col_l];
  const unsigned short* Tb = (const unsigned short*)ws
      + (size_t)wv * 20480 + col_l * 32 + quad * 8;

  bf16x8 bq[4];
#pragma unroll
  for (int c = 0; c < 4; ++c)
    bq[c] = *(const bf16x8*)(Tb + (size_t)(36 + c) * 512);
  bf16x8 b0[9];
#pragma unroll
  for (int f = 0; f < 9; ++f)
    b0[f] = *(const bf16x8*)(Tb + (size_t)f * 512);

  // ---- convert X = [bf16(y), bf16(y^2)] into sX: 512 granules, 2/thread ----
  {
#pragma unroll
    for (int j = 0; j < 2; ++j) {
      const int idx = tid + j * 256;        // granule 0..511
      const int row = idx >> 5, g = idx & 31;
      const float4* ya = (const float4*)y + (size_t)(r0 + row) * 32 + (g & 15) * 2;
      float4 a = ya[0], b = ya[1];
      if (g >= 16) {
        a.x *= a.x; a.y *= a.y; a.z *= a.z; a.w *= a.w;
        b.x *= b.x; b.y *= b.y; b.z *= b.z; b.w *= b.w;
      }
      union { unsigned short us[8]; uint4 v; } o;
      o.us[0] = f2bf(a.x); o.us[1] = f2bf(a.y); o.us[2] = f2bf(a.z); o.us[3] = f2bf(a.w);
      o.us[4] = f2bf(b.x); o.us[5] = f2bf(b.y); o.us[6] = f2bf(b.z); o.us[7] = f2bf(b.w);
      *(uint4*)(sX + row * XSTR + g * 8) = o.v;
    }
  }

  __syncthreads();   // X conversion complete; only barrier before epilogue

  bf16x8 a[8];
#pragma unroll
  for (int c = 0; c < 8; ++c)
    a[c] = *(const bf16x8*)(sX + col_l * XSTR + c * 32 + quad * 8);

  f32x4 acc[9];
#pragma unroll
  for (int f = 0; f < 9; ++f) { acc[f][0] = 0.f; acc[f][1] = 0.f; acc[f][2] = 0.f; acc[f][3] = 0.f; }

  // chunk 0 from preloaded registers
#pragma unroll
  for (int f = 0; f < 9; ++f)
    acc[f] = __builtin_amdgcn_mfma_f32_16x16x32_bf16(a[0], b0[f], acc[f], 0, 0, 0);
  // chunks 1..3: 27 coalesced 1KB loads + 27 MFMAs, no barriers
#pragma unroll
  for (int c = 1; c < 4; ++c) {
    bf16x8 b[9];
#pragma unroll
    for (int f = 0; f < 9; ++f)
      b[f] = *(const bf16x8*)(Tb + (size_t)(c * 9 + f) * 512);
#pragma unroll
    for (int f = 0; f < 9; ++f)
      acc[f] = __builtin_amdgcn_mfma_f32_16x16x32_bf16(a[c], b[f], acc[f], 0, 0, 0);
  }
  // diag term: y^2 chunks contribute only to acc[8]
#pragma unroll
  for (int c = 0; c < 4; ++c)
    acc[8] = __builtin_amdgcn_mfma_f32_16x16x32_bf16(a[4 + c], bq[c], acc[8], 0, 0, 0);

  // ---- epilogue: per-k logits in registers ----
  // thread owns k = wv*16 + col_l, rows quad*4 + reg
#pragma unroll
  for (int reg = 0; reg < 4; ++reg) {
    float v = acc[8][reg];                  // linear + diag term
#pragma unroll
    for (int cc = 0; cc < 8; ++cc) v += acc[cc][reg] * acc[cc][reg];
    vals2[(quad * 4 + reg) * 66 + wv * 16 + col_l] = cv + v;
  }
  __syncthreads();

  // per-row 64-k logsumexp: wave wv handles rows wv*4..wv*4+3, lane = k
#pragma unroll
  for (int rr = 0; rr < 4; ++rr) {
    const int row = wv * 4 + rr;
    const float val = vals2[row * 66 + lane];
    float mx = val;
#pragma unroll
    for (int off = 1; off < 64; off <<= 1)
      mx = fmaxf(mx, __shfl_xor(mx, off, 64));
    float ex = expf(val - mx);
#pragma unroll
    for (int off = 1; off < 64; off <<= 1)
      ex += __shfl_xor(ex, off, 64);
    if (lane == 0) out[r0 + row] = mx + logf(ex);
  }
}

extern "C" void kernel_launch(void* const* d_in, const int* in_sizes, int n_in,
                              void* d_out, int out_size, void* d_ws, size_t ws_size,
                              hipStream_t stream) {
  const float* y     = (const float*)d_in[0];
  const float* m     = (const float*)d_in[1];
  const float* delta = (const float*)d_in[2];
  const float* U     = (const float*)d_in[3];
  const float* lar   = (const float*)d_in[4];
  float* out = (float*)d_out;
  float* ws  = (float*)d_ws;

  precomp_kernel<<<K_DIM, 128, 0, stream>>>(m, delta, U, lar, ws);
  logz_full<<<B_DIM / 16, 256, 0, stream>>>(y, ws, out);
}